// Round 3
// baseline (258.002 us; speedup 1.0000x reference)
//
#include <hip/hip_runtime.h>

// ZNCC fused streaming kernel. [16,3,512,512] f32 -> [16,1,512,512] f32.
// 5x5 box means, zero pad, /25 everywhere; second box over centered products.
//
// Structure: register-resident vertical rolling sums, horizontal sums in
// registers from overlapping per-lane loads (halo via cache, not LDS).
// Block = 192 threads = 3 waves, one per channel, for one (b, seg, strip).
// Each lane owns NOUT=4 output cols; wave covers a 256-col strip; rows
// streamed in an HS-row segment (+8 halo rows re-streamed).
//
// R1: HS 32->8 + launch_bounds(192,6): VGPR capped at 40 -> scratch spill
//     (WRITE 475MB), 3.2x regression. R2: pragma dropped: spill gone,
//     occupancy still ~16%, VALUBusy 28 -> latency-bound INSIDE each wave.
// R3: branch-free hot path. Row guards (runtime o0) forced every load group
//     into its own branch region -> 3 serial vmcnt(0) waits per iter.
//     (a) seg 1..62 take a guard-free template instantiation (all row
//     guards statically true); (b) per-lane okA/okC exec-mask branches
//     replaced by clamped aligned offsets + fmaf 0/1-mask on the 2 edge
//     values (same instr count as add/sub). All loads unconditional ->
//     compiler can software-pipeline across the unrolled iterations.

constexpr int W = 512, H = 512, Cn = 3, Bn = 16;
constexpr int HS = 8;        // output rows per segment
constexpr int NITER = HS + 8;
constexpr int STRIPW = 256;  // output cols per wave strip
constexpr int NOUT = 4;      // output cols per lane
constexpr int NSEG = H / HS;

__device__ __forceinline__ void load12(const float* __restrict__ rb, int oA,
                                       int oM, int oC, float* d) {
    // three unconditional float4 loads; rb is wave-uniform (row base),
    // oA/oM/oC are per-lane element offsets (precomputed, clamped, aligned).
    float4 a = *(const float4*)(rb + oA);
    float4 b = *(const float4*)(rb + oM);
    float4 c = *(const float4*)(rb + oC);
    d[0] = a.x; d[1] = a.y; d[2]  = a.z; d[3]  = a.w;
    d[4] = b.x; d[5] = b.y; d[6]  = b.z; d[7]  = b.w;
    d[8] = c.x; d[9] = c.y; d[10] = c.z; d[11] = c.w;
}

template <bool BOUND>
__device__ __forceinline__ void seg_body(
    const float* __restrict__ xp, const float* __restrict__ yp,
    float* __restrict__ acc, int o0, int lane, int m0,
    int oA, int oM, int oC, float mA, float mAn, float mC, float mCn) {

    // product-column validity masks (cols m0-2+i). Also kills any products
    // built from the clamped/garbage edge-lane values (finite data, so 0*x=0).
    float pm[8];
#pragma unroll
    for (int i = 0; i < 8; ++i) {
        int col = m0 - 2 + i;
        pm[i] = (col >= 0 && col < W) ? 1.f : 0.f;
    }

    float vsx[12], vsy[12];                        // rolling vertical 5-row raw sums
    float qxx[5][4], qxy[5][4], qyy[5][4];         // hp queue (5-deep)
    float oxx[4], oxy[4], oyy[4];                  // rolling vertical hp sums
#pragma unroll
    for (int i = 0; i < 12; ++i) { vsx[i] = 0.f; vsy[i] = 0.f; }
#pragma unroll
    for (int s = 0; s < 5; ++s)
#pragma unroll
        for (int j = 0; j < 4; ++j) { qxx[s][j] = 0.f; qxy[s][j] = 0.f; qyy[s][j] = 0.f; }
#pragma unroll
    for (int j = 0; j < 4; ++j) { oxx[j] = 0.f; oxy[j] = 0.f; oyy[j] = 0.f; }

    // iter k: load raw row L = o0-4+k; vsum covers rows L-4..L (center V = L-2);
    // products/hp at row V (k>=4); output row O = L-4 = o0-8+k (k>=8).
    // Interior segments (1..NSEG-2): Lold in [4,502], L in [4,507], V in [6,505]
    // -> all row guards statically true when !BOUND.
#pragma unroll
    for (int k = 0; k < NITER; ++k) {
        const int u = k % 5;   // queue slot: compile-time constant after unroll
        const int L = o0 - 4 + k;
        const int Lold = L - 5;

        // subtract row L-5 (added 5 iters ago; L1-hot re-read)
        if (k >= 5 && (!BOUND || Lold >= 0)) {
            float ox[12], oy[12];
            load12(xp + (size_t)Lold * W, oA, oM, oC, ox);
            load12(yp + (size_t)Lold * W, oA, oM, oC, oy);
            vsx[0] -= ox[0]; vsx[1] -= ox[1];
            vsx[2] = fmaf(ox[2], mAn, vsx[2]); vsx[3] = fmaf(ox[3], mAn, vsx[3]);
#pragma unroll
            for (int i = 4; i < 8; ++i) vsx[i] -= ox[i];
            vsx[8] = fmaf(ox[8], mCn, vsx[8]); vsx[9] = fmaf(ox[9], mCn, vsx[9]);
            vsx[10] -= ox[10]; vsx[11] -= ox[11];

            vsy[0] -= oy[0]; vsy[1] -= oy[1];
            vsy[2] = fmaf(oy[2], mAn, vsy[2]); vsy[3] = fmaf(oy[3], mAn, vsy[3]);
#pragma unroll
            for (int i = 4; i < 8; ++i) vsy[i] -= oy[i];
            vsy[8] = fmaf(oy[8], mCn, vsy[8]); vsy[9] = fmaf(oy[9], mCn, vsy[9]);
            vsy[10] -= oy[10]; vsy[11] -= oy[11];
        }
        // add new row L
        if (!BOUND || (L >= 0 && L < H)) {
            float nx[12], ny[12];
            load12(xp + (size_t)L * W, oA, oM, oC, nx);
            load12(yp + (size_t)L * W, oA, oM, oC, ny);
            vsx[0] += nx[0]; vsx[1] += nx[1];
            vsx[2] = fmaf(nx[2], mA, vsx[2]); vsx[3] = fmaf(nx[3], mA, vsx[3]);
#pragma unroll
            for (int i = 4; i < 8; ++i) vsx[i] += nx[i];
            vsx[8] = fmaf(nx[8], mC, vsx[8]); vsx[9] = fmaf(nx[9], mC, vsx[9]);
            vsx[10] += nx[10]; vsx[11] += nx[11];

            vsy[0] += ny[0]; vsy[1] += ny[1];
            vsy[2] = fmaf(ny[2], mA, vsy[2]); vsy[3] = fmaf(ny[3], mA, vsy[3]);
#pragma unroll
            for (int i = 4; i < 8; ++i) vsy[i] += ny[i];
            vsy[8] = fmaf(ny[8], mC, vsy[8]); vsy[9] = fmaf(ny[9], mC, vsy[9]);
            vsy[10] += ny[10]; vsy[11] += ny[11];
        }

        if (k >= 4) {
            // retire hp row V-5 from rolling output sums (slot u, about to be overwritten)
#pragma unroll
            for (int j = 0; j < 4; ++j) {
                oxx[j] -= qxx[u][j]; oxy[j] -= qxy[u][j]; oyy[j] -= qyy[u][j];
            }
            const int V = L - 2;
            if (!BOUND || (V >= 0 && V < H)) {
                // 25-sums (means*25) at mid cols m0-2+i via incremental h-sum
                float mx[8], my[8];
                mx[0] = vsx[0] + vsx[1] + vsx[2] + vsx[3] + vsx[4];
                my[0] = vsy[0] + vsy[1] + vsy[2] + vsy[3] + vsy[4];
#pragma unroll
                for (int i = 1; i < 8; ++i) {
                    mx[i] = mx[i - 1] - vsx[i - 1] + vsx[i + 4];
                    my[i] = my[i - 1] - vsy[i - 1] + vsy[i + 4];
                }
                // center row raw (re-read; L1 hot — loaded 2 iters ago)
                float cx[12], cyv[12];
                load12(xp + (size_t)V * W, oA, oM, oC, cx);
                load12(yp + (size_t)V * W, oA, oM, oC, cyv);

                float pxx[8], pxy[8], pyy[8];
#pragma unroll
                for (int i = 0; i < 8; ++i) {
                    float xc = (cx[i + 2]  - mx[i] * 0.04f) * pm[i];
                    float yc = (cyv[i + 2] - my[i] * 0.04f) * pm[i];
                    pxx[i] = xc * xc; pxy[i] = xc * yc; pyy[i] = yc * yc;
                }
                // horizontal 5-sum of products -> 4 outputs; push + add to rolling sums
                float h;
                h = pxx[0] + pxx[1] + pxx[2] + pxx[3] + pxx[4];
                qxx[u][0] = h; oxx[0] += h;
#pragma unroll
                for (int j = 1; j < 4; ++j) {
                    h = h - pxx[j - 1] + pxx[j + 4]; qxx[u][j] = h; oxx[j] += h;
                }
                h = pxy[0] + pxy[1] + pxy[2] + pxy[3] + pxy[4];
                qxy[u][0] = h; oxy[0] += h;
#pragma unroll
                for (int j = 1; j < 4; ++j) {
                    h = h - pxy[j - 1] + pxy[j + 4]; qxy[u][j] = h; oxy[j] += h;
                }
                h = pyy[0] + pyy[1] + pyy[2] + pyy[3] + pyy[4];
                qyy[u][0] = h; oyy[0] += h;
#pragma unroll
                for (int j = 1; j < 4; ++j) {
                    h = h - pyy[j - 1] + pyy[j + 4]; qyy[u][j] = h; oyy[j] += h;
                }
            } else {
                // padding row: products are zero
#pragma unroll
                for (int j = 0; j < 4; ++j) { qxx[u][j] = 0.f; qxy[u][j] = 0.f; qyy[u][j] = 0.f; }
            }

            if (k >= 8) {
                const int r = k - 8;  // output row within segment
#pragma unroll
                for (int j = 0; j < 4; ++j) {
                    // ncc = (Sxy/25) / (sqrt(Sxx/25)*sqrt(Syy/25) + 1e-8)
                    //     = Sxy / (sqrt(Sxx*Syy) + 25e-8)
                    float rad = fmaxf(oxx[j] * oyy[j], 0.f);  // guard rolling drift
                    float s = sqrtf(rad) + 2.5e-7f;
                    float ncc = oxy[j] * __builtin_amdgcn_rcpf(s);
                    atomicAdd(&acc[r * STRIPW + lane * NOUT + j], ncc);
                }
            }
        }
    }
}

__global__ __launch_bounds__(192) void zncc_stream(const float* __restrict__ xg,
                                                   const float* __restrict__ yg,
                                                   float* __restrict__ outg) {
    __shared__ float acc[HS * STRIPW];  // 8 KB

    const int tid  = threadIdx.x;
    const int lane = tid & 63;
    const int ch   = tid >> 6;          // wave -> channel
    const int bx   = blockIdx.x;        // seg*2 + strip
    const int seg  = bx >> 1;
    const int strip = bx & 1;
    const int b    = blockIdx.y;
    const int o0   = seg * HS;

    // zero the LDS accumulator
    for (int i = tid; i < HS * STRIPW / 4; i += 192)
        ((float4*)acc)[i] = make_float4(0.f, 0.f, 0.f, 0.f);
    __syncthreads();

    const float* __restrict__ xp = xg + ((size_t)(b * Cn + ch)) * (H * W);
    const float* __restrict__ yp = yg + ((size_t)(b * Cn + ch)) * (H * W);

    const int m0 = strip * STRIPW + lane * NOUT;  // first output col
    const int c0 = m0 - 4;                        // first raw col (12-wide span)
    const bool okA = (c0 >= 0);                   // fails only lane 0, strip 0
    const bool okC = (c0 + 8 < W);                // fails only lane 63, strip 1

    // clamped, 16B-aligned per-lane load offsets (elements)
    const int oA = okA ? c0 : 0;
    const int oM = c0 + 4;
    const int oC = okC ? (c0 + 8) : (c0 + 4);
    // 0/1 masks for the 2 edge values each clamp contaminates (vsx[2,3]/vsx[8,9]);
    // remaining clamped values only feed pm-killed products (finite data, safe).
    const float mA = okA ? 1.f : 0.f, mAn = -mA;
    const float mC = okC ? 1.f : 0.f, mCn = -mC;

    if (seg == 0 || seg == NSEG - 1)
        seg_body<true>(xp, yp, acc, o0, lane, m0, oA, oM, oC, mA, mAn, mC, mCn);
    else
        seg_body<false>(xp, yp, acc, o0, lane, m0, oA, oM, oC, mA, mAn, mC, mCn);

    __syncthreads();
    // writeout: mean over 3 channels
    const float inv3 = 1.f / 3.f;
    float* op = outg + (size_t)b * (H * W);
    for (int i = tid; i < HS * STRIPW / 4; i += 192) {
        float4 v = ((const float4*)acc)[i];
        v.x *= inv3; v.y *= inv3; v.z *= inv3; v.w *= inv3;
        int r = i / (STRIPW / 4);
        int c4 = i - r * (STRIPW / 4);
        *(float4*)(op + (size_t)(o0 + r) * W + strip * STRIPW + c4 * 4) = v;
    }
}

extern "C" void kernel_launch(void* const* d_in, const int* in_sizes, int n_in,
                              void* d_out, int out_size, void* d_ws, size_t ws_size,
                              hipStream_t stream) {
    const float* x = (const float*)d_in[0];
    const float* y = (const float*)d_in[1];
    float* out = (float*)d_out;
    dim3 grid((H / HS) * (W / STRIPW), Bn);  // 128 x 16 blocks
    zncc_stream<<<grid, 192, 0, stream>>>(x, y, out);
}